// Round 1
// 3480.837 us; speedup vs baseline: 1.1545x; 1.1545x over previous
//
#include <hip/hip_runtime.h>
#include <cstdint>
#include <cstddef>

// ---------------------------------------------------------------------------
// Transformer (enc-dec) forward on MI355X. Round 2:
//  - all weights pre-transposed+converted to bf16 [N,K] once per forward
//  - gemm_k: B staged via global_load_lds (16B), unpadded conflict-free LDS,
//    both MFMA fragments ds_read_b128; XCD-chunked m-fastest block swizzle
//  - V written transposed-bf16 by the producing GEMM epilogue; pv_k fully
//    vectorized via global_load_lds
// Workspace requirement: ~180 MB (weights bf16 region at +76 MB).
// ---------------------------------------------------------------------------

#define B_   4
#define S_   512
#define D_   512
#define H_   8
#define L_   6
#define DFF_ 2048
#define VD_  32000

typedef unsigned short u16;
typedef short  s16x8  __attribute__((ext_vector_type(8)));
typedef __bf16 bf16x8 __attribute__((ext_vector_type(8)));
typedef float  f32x4  __attribute__((ext_vector_type(4)));

__device__ __forceinline__ u16 f2b(float f) {
    __bf16 h = (__bf16)f; return __builtin_bit_cast(u16, h);
}
__device__ __forceinline__ bf16x8 ld_frag(const u16* p) {
    return __builtin_bit_cast(bf16x8, *(const s16x8*)p);
}
// load 8 consecutive floats, convert to bf16, store 16B to LDS
__device__ __forceinline__ void cvt8(const float* __restrict__ g, u16* l) {
    float4 x = *(const float4*)g;
    float4 y = *(const float4*)(g + 4);
    bf16x8 o;
    o[0] = (__bf16)x.x; o[1] = (__bf16)x.y; o[2] = (__bf16)x.z; o[3] = (__bf16)x.w;
    o[4] = (__bf16)y.x; o[5] = (__bf16)y.y; o[6] = (__bf16)y.z; o[7] = (__bf16)y.w;
    *(s16x8*)l = __builtin_bit_cast(s16x8, o);
}
// async 16B global -> LDS (dest = wave-uniform base + lane*16)
__device__ __forceinline__ void gload16(const u16* g, u16* l) {
    __builtin_amdgcn_global_load_lds(
        (const __attribute__((address_space(1))) unsigned int*)(const void*)g,
        (__attribute__((address_space(3))) unsigned int*)(void*)l, 16, 0, 0);
}
__device__ __forceinline__ float wsum(float x) {
#pragma unroll
    for (int m = 32; m > 0; m >>= 1) x += __shfl_xor(x, m, 64);
    return x;
}
__device__ __forceinline__ float wmaxr(float x) {
#pragma unroll
    for (int m = 32; m > 0; m >>= 1) x = fmaxf(x, __shfl_xor(x, m, 64));
    return x;
}

// ---------------------------------------------------------------------------
// Weight transpose+convert: in fp32 [K,N] -> out bf16 [N,K].
// z indexes (tensor, layer): t = z/Lc selects in0..in3, l = z%Lc.
// Block: 64k x 64n tile. Reads coalesced (lane = n); writes 16B/lane,
// 4 waves cover each 64B line concurrently (L2 assembles).
// ---------------------------------------------------------------------------
__global__ __launch_bounds__(256) void wt_k(const float* __restrict__ in0,
                                            const float* __restrict__ in1,
                                            const float* __restrict__ in2,
                                            const float* __restrict__ in3,
                                            u16* __restrict__ out,
                                            int K, int N, int Lc)
{
    const int z = blockIdx.z;
    const int tsel = z / Lc, l = z % Lc;
    const float* in = tsel == 0 ? in0 : tsel == 1 ? in1 : tsel == 2 ? in2 : in3;
    in += (size_t)l * K * N;
    u16* o = out + (size_t)z * K * N;

    const int n0 = blockIdx.x * 64, k0 = blockIdx.y * 64;
    const int tt = threadIdx.x;
    const int n = tt & 63, kq = tt >> 6;     // n 0..63, kq 0..3
#pragma unroll
    for (int it = 0; it < 2; ++it) {
        int k8 = kq + it * 4;                // 0..7
        bf16x8 ov;
#pragma unroll
        for (int j = 0; j < 8; ++j)
            ov[j] = (__bf16)in[(size_t)(k0 + k8 * 8 + j) * N + n0 + n];
        *(s16x8*)(o + (size_t)(n0 + n) * K + k0 + k8 * 8) =
            __builtin_bit_cast(s16x8, ov);
    }
}

// ---------------------------------------------------------------------------
// Embedding + positional encoding (fp32 in/out).
// ---------------------------------------------------------------------------
__global__ __launch_bounds__(256) void embed_k(const int* __restrict__ idx,
                                               const float* __restrict__ emb,
                                               float* __restrict__ out)
{
    int rs = blockIdx.x;          // [0, B*S)
    int s  = rs & (S_ - 1);
    int tok = idx[rs];
#pragma unroll
    for (int i = 0; i < 2; ++i) {
        int d = threadIdx.x + i * 256;
        float e  = emb[(size_t)tok * D_ + d];
        float pe = 0.0f;
        if (s > 0 && d > 0) {
            float ang = (float)s * expf(-(float)d * 0.035977892078031968f); // ln(1e4)/256
            pe = (d & 1) ? cosf(ang) : sinf(ang);
        }
        out[(size_t)rs * D_ + d] = e + pe;
    }
}

// ---------------------------------------------------------------------------
// GEMM: C[M,N] = act(A[M,K] @ B + bias). A fp32 row-major (cvt at staging);
// B bf16 PRE-TRANSPOSED [N,K]. 128x128 tile, BK=32, 256 thr, 16x16x32 MFMA.
// grid.x = (M/128)*(N/128) with XCD-chunked swizzle, m-tile fastest.
// blockIdx.z selects one of up to 3 (B, bias, O, T) tuples.
// If T != 0: output written ONLY as transposed bf16 V: T[((b*8+h)*64+d)*512+s]
// where b=row>>9, s=row&511, h=col>>6, d=col&63 (for attention V).
// ---------------------------------------------------------------------------
__global__ __launch_bounds__(256) void gemm_k(
    const float* __restrict__ A,
    const u16* B0, const u16* B1, const u16* B2,
    const float* bias0, const float* bias1, const float* bias2,
    float* O0, float* O1, float* O2,
    u16* T0, u16* T1, u16* T2,
    int M, int N, int K, int act)
{
    const u16* Bt     = blockIdx.z == 0 ? B0 : (blockIdx.z == 1 ? B1 : B2);
    const float* bias = blockIdx.z == 0 ? bias0 : (blockIdx.z == 1 ? bias1 : bias2);
    float* O          = blockIdx.z == 0 ? O0 : (blockIdx.z == 1 ? O1 : O2);
    u16* Tt           = blockIdx.z == 0 ? T0 : (blockIdx.z == 1 ? T1 : T2);

    __shared__ u16 As[128 * 32];   // [m][k] bf16, unpadded (stride-1 perm reads)
    __shared__ u16 Bs[128 * 32];   // [n][k] bf16, unpadded

    const int t = threadIdx.x;
    const int lane = t & 63, wave = t >> 6;
    const int q = lane >> 4, r16 = lane & 15;
    const int wm = (wave & 1) * 64, wn = (wave >> 1) * 64;

    // XCD-chunked bijective swizzle (nwg always %8==0 here), m-tile fastest
    const int nwg = gridDim.x;
    const int orig = blockIdx.x;
    const int qq = nwg >> 3, rr = nwg & 7;
    const int xcd = orig & 7, loc = orig >> 3;
    const int wg = (xcd < rr ? xcd * (qq + 1) : rr * (qq + 1) + (xcd - rr) * qq) + loc;
    const int mt = M >> 7;
    const int m0 = (wg % mt) * 128, n0 = (wg / mt) * 128;

    f32x4 acc[4][4] = {};

    for (int k0 = 0; k0 < K; k0 += 32) {
#pragma unroll
        for (int r = 0; r < 2; ++r) {                 // A tile 128x32 fp32->bf16
            int uu = t + r * 256;
            int row = uu >> 2, c8 = uu & 3;
            cvt8(A + (size_t)(m0 + row) * K + k0 + c8 * 8, As + row * 32 + c8 * 8);
        }
#pragma unroll
        for (int r = 0; r < 2; ++r) {                 // B tile 128n x 32k, direct
            int c = wave * 2 + r;                     // chunk = 16 n-rows = 1 KB
            gload16(Bt + (size_t)(n0 + c * 16 + (lane >> 2)) * K + k0 + (lane & 3) * 8,
                    Bs + c * 512);
        }
        __syncthreads();

        bf16x8 af[4], bf[4];
#pragma unroll
        for (int fm = 0; fm < 4; ++fm)
            af[fm] = ld_frag(As + (wm + fm * 16 + r16) * 32 + q * 8);
#pragma unroll
        for (int fn = 0; fn < 4; ++fn)
            bf[fn] = ld_frag(Bs + (wn + fn * 16 + r16) * 32 + q * 8);
#pragma unroll
        for (int fm = 0; fm < 4; ++fm)
#pragma unroll
            for (int fn = 0; fn < 4; ++fn)
                acc[fm][fn] = __builtin_amdgcn_mfma_f32_16x16x32_bf16(
                    af[fm], bf[fn], acc[fm][fn], 0, 0, 0);
        __syncthreads();
    }

#pragma unroll
    for (int fn = 0; fn < 4; ++fn) {
        int col = n0 + wn + fn * 16 + r16;
        float bv = bias ? bias[col] : 0.0f;
#pragma unroll
        for (int fm = 0; fm < 4; ++fm) {
            int rb = m0 + wm + fm * 16 + q * 4;       // C: col=lane&15, row=quad*4+reg
            if (Tt) {
                // transposed bf16 V store: 4 consecutive k packed into 8B
                u16 w0 = f2b(acc[fm][fn][0] + bv), w1 = f2b(acc[fm][fn][1] + bv);
                u16 w2 = f2b(acc[fm][fn][2] + bv), w3 = f2b(acc[fm][fn][3] + bv);
                uint2 pk;
                pk.x = (unsigned)w0 | ((unsigned)w1 << 16);
                pk.y = (unsigned)w2 | ((unsigned)w3 << 16);
                *(uint2*)(Tt + (((size_t)((rb >> 9) * 8 + (col >> 6)) * 64 + (col & 63)) << 9)
                             + (rb & 511)) = pk;
            } else {
#pragma unroll
                for (int rg = 0; rg < 4; ++rg) {
                    float x = acc[fm][fn][rg] + bv;
                    if (act) x = x >= 0.0f ? x : 0.01f * x;
                    O[(size_t)(rb + rg) * N + col] = x;
                }
            }
        }
    }
}

// ---------------------------------------------------------------------------
// Attention scores: Sc[bh,q,k] = (Q . K)/8, fp32 out. grid (4,4,B*H).
// ---------------------------------------------------------------------------
__global__ __launch_bounds__(256) void scores_k(const float* __restrict__ Qb,
                                                const float* __restrict__ Kb,
                                                float* __restrict__ Sc)
{
    __shared__ u16 Qs[128 * 72];
    __shared__ u16 Ks[128 * 72];
    const int t = threadIdx.x;
    const int lane = t & 63, wave = t >> 6;
    const int q = lane >> 4, r16 = lane & 15;
    const int wm = (wave & 1) * 64, wn = (wave >> 1) * 64;
    const int n0 = blockIdx.x * 128, m0 = blockIdx.y * 128;
    const int bh = blockIdx.z, b = bh >> 3, h = bh & 7;
    const size_t base = (size_t)b * S_ * D_ + h * 64;

#pragma unroll
    for (int r = 0; r < 4; ++r) {
        int uu = t + r * 256;
        int row = uu >> 3, c8 = uu & 7;
        cvt8(Qb + base + (size_t)(m0 + row) * D_ + c8 * 8, Qs + row * 72 + c8 * 8);
        cvt8(Kb + base + (size_t)(n0 + row) * D_ + c8 * 8, Ks + row * 72 + c8 * 8);
    }
    __syncthreads();

    f32x4 acc[4][4] = {};
#pragma unroll
    for (int kk = 0; kk < 2; ++kk) {
        bf16x8 af[4], bf[4];
#pragma unroll
        for (int fm = 0; fm < 4; ++fm)
            af[fm] = ld_frag(Qs + (wm + fm * 16 + r16) * 72 + kk * 32 + q * 8);
#pragma unroll
        for (int fn = 0; fn < 4; ++fn)
            bf[fn] = ld_frag(Ks + (wn + fn * 16 + r16) * 72 + kk * 32 + q * 8);
#pragma unroll
        for (int fm = 0; fm < 4; ++fm)
#pragma unroll
            for (int fn = 0; fn < 4; ++fn)
                acc[fm][fn] = __builtin_amdgcn_mfma_f32_16x16x32_bf16(
                    af[fm], bf[fn], acc[fm][fn], 0, 0, 0);
    }

#pragma unroll
    for (int fn = 0; fn < 4; ++fn) {
        int col = n0 + wn + fn * 16 + r16;
#pragma unroll
        for (int fm = 0; fm < 4; ++fm)
#pragma unroll
            for (int rg = 0; rg < 4; ++rg) {
                int rowg = m0 + wm + fm * 16 + q * 4 + rg;
                Sc[((size_t)bh * S_ + rowg) * S_ + col] = 0.125f * acc[fm][fn][rg];
            }
    }
}

// ---------------------------------------------------------------------------
// Mask + softmax. Masked entries = 1e-9 BEFORE softmax. Wave per row; P bf16.
// ---------------------------------------------------------------------------
__global__ __launch_bounds__(256) void softmax_k(const float* __restrict__ Sc,
                                                 u16* __restrict__ P,
                                                 const int* __restrict__ tok,
                                                 int causal)
{
    const int wave = threadIdx.x >> 6, lane = threadIdx.x & 63;
    const int row = blockIdx.x * 4 + wave;      // [0, B*H*S)
    const int qi = row & (S_ - 1), b = row >> 12;
    const float* sr = Sc + (size_t)row * S_;
    const int* kb = tok + b * S_;

    float v[8];
    float mx = -3.0e38f;
#pragma unroll
    for (int i = 0; i < 8; ++i) {
        int k = i * 64 + lane;
        float x = sr[k];
        bool msk = (kb[k] == 0) || (causal && (k > qi));
        x = msk ? 1e-9f : x;
        v[i] = x;
        mx = fmaxf(mx, x);
    }
    mx = wmaxr(mx);
    float s = 0.0f;
#pragma unroll
    for (int i = 0; i < 8; ++i) { v[i] = __expf(v[i] - mx); s += v[i]; }
    s = wsum(s);
    float inv = 1.0f / s;
#pragma unroll
    for (int i = 0; i < 8; ++i)
        P[(size_t)row * S_ + i * 64 + lane] = f2b(v[i] * inv);
}

// ---------------------------------------------------------------------------
// PV: attn[b, q, h*64+d] = sum_k P[bh,q,k] * Vt[bh,d,k]. grid (S/64, B*H).
// P bf16 [row][k]; Vt bf16 [bh][d][k] (written transposed by gemm_k).
// Both LDS tiles unpadded, staged via vector copy / global_load_lds;
// all fragment reads ds_read_b128, conflict-free.
// ---------------------------------------------------------------------------
__global__ __launch_bounds__(256) void pv_k(const u16* __restrict__ P,
                                            const u16* __restrict__ Vt,
                                            float* __restrict__ attnb)
{
    __shared__ u16 Ps[64 * 32];   // [m][k]
    __shared__ u16 Vs[64 * 32];   // [d][k]
    const int t = threadIdx.x;
    const int lane = t & 63, wave = t >> 6;
    const int q = lane >> 4, r16 = lane & 15;
    const int m0 = blockIdx.x * 64;
    const int bh = blockIdx.y, b = bh >> 3, h = bh & 7;

    f32x4 acc[4] = {};
    for (int k0 = 0; k0 < S_; k0 += 32) {
        {
            int row = t >> 2, c8 = t & 3;           // P tile 64x32 bf16 copy
            *(uint4*)(Ps + row * 32 + c8 * 8) =
                *(const uint4*)(P + ((size_t)bh * S_ + m0 + row) * S_ + k0 + c8 * 8);
            // V tile 64d x 32k direct from transposed global
            gload16(Vt + ((size_t)bh * 64 + wave * 16 + (lane >> 2)) * S_ + k0 + (lane & 3) * 8,
                    Vs + wave * 512);
        }
        __syncthreads();
        bf16x8 a = ld_frag(Ps + (wave * 16 + r16) * 32 + q * 8);
#pragma unroll
        for (int fn = 0; fn < 4; ++fn)
            acc[fn] = __builtin_amdgcn_mfma_f32_16x16x32_bf16(
                a, ld_frag(Vs + (fn * 16 + r16) * 32 + q * 8), acc[fn], 0, 0, 0);
        __syncthreads();
    }
#pragma unroll
    for (int fn = 0; fn < 4; ++fn)
#pragma unroll
        for (int rg = 0; rg < 4; ++rg)
            attnb[((size_t)b * S_ + m0 + wave * 16 + q * 4 + rg) * D_ + h * 64 + fn * 16 + r16]
                = acc[fn][rg];
}

// ---------------------------------------------------------------------------
// LayerNorm: out = LN(x32 + resid) * g + b  (wave per row of 512, fp32)
// ---------------------------------------------------------------------------
__global__ __launch_bounds__(256) void ln_k(const float* __restrict__ X32,
                                            const float* resid,
                                            const float* __restrict__ g,
                                            const float* __restrict__ be,
                                            float* out)
{
    const int wave = threadIdx.x >> 6, lane = threadIdx.x & 63;
    const int row = blockIdx.x * 4 + wave;
    const float* xr = X32 + (size_t)row * D_;
    const float* rr = resid + (size_t)row * D_;

    float v[8];
    float s = 0.0f;
#pragma unroll
    for (int i = 0; i < 8; ++i) {
        v[i] = xr[i * 64 + lane] + rr[i * 64 + lane];
        s += v[i];
    }
    s = wsum(s);
    float mean = s * (1.0f / D_);
    float s2 = 0.0f;
#pragma unroll
    for (int i = 0; i < 8; ++i) { float d = v[i] - mean; s2 += d * d; }
    s2 = wsum(s2);
    float inv = rsqrtf(s2 * (1.0f / D_) + 1e-6f);
#pragma unroll
    for (int i = 0; i < 8; ++i) {
        int c = i * 64 + lane;
        out[(size_t)row * D_ + c] = (v[i] - mean) * inv * g[c] + be[c];
    }
}

// ---------------------------------------------------------------------------
// Host-side orchestration
// ---------------------------------------------------------------------------
extern "C" void kernel_launch(void* const* d_in, const int* in_sizes, int n_in,
                              void* d_out, int out_size, void* d_ws, size_t ws_size,
                              hipStream_t stream)
{
    (void)in_sizes; (void)n_in; (void)out_size; (void)ws_size;

    const int*   enc_in  = (const int*)d_in[0];
    const int*   dec_in  = (const int*)d_in[1];
    const float* emb_enc = (const float*)d_in[2];
    const float* emb_dec = (const float*)d_in[3];
    const float* proj_W  = (const float*)d_in[4];
    // per prefix: 0 Wq 1 Wk 2 Wv 3 Wo 4 g1 5 b1 6 W1 7 c1 8 W2 9 c2 10 g2 11 b2
    const float* Wt[2][12];
    for (int p = 0; p < 2; ++p)
        for (int j = 0; j < 12; ++j)
            Wt[p][j] = (const float*)d_in[5 + p * 12 + j];

    // workspace layout (1 MB units). fp32 scratch 0..76 MB, bf16 weights after.
    char* ws = (char*)d_ws;
    const size_t MB = 1024 * 1024;
    float* Xe  = (float*)(ws + 0 * MB);    // [2048,512] f32 (enc act / enc_out)
    float* Xd  = (float*)(ws + 4 * MB);    // [2048,512] f32 (dec act)
    float* Qb  = (float*)(ws + 8 * MB);
    float* Kb  = (float*)(ws + 12 * MB);
    u16*   Vt  = (u16*)  (ws + 16 * MB);   // V transposed bf16 [32][64][512], 2 MB
    float* Atn = (float*)(ws + 20 * MB);   // attention context [2048,512]
    float* Fo  = (float*)(ws + 24 * MB);   // pre-LN matmul out [2048,512]
    float* Sc  = (float*)(ws + 28 * MB);   // scores [32,512,512] f32, 32 MB
    float* Hid = (float*)(ws + 28 * MB);   // FFN hidden [2048,2048] f32 (shares w/ Sc)
    u16*   Pm  = (u16*)  (ws + 60 * MB);   // probs [32,512,512] bf16, 16 MB

    // bf16 transposed weights: 76 MB .. ~179.3 MB
    u16* WTb = (u16*)(ws + 76 * MB);
    const size_t T66 = (size_t)6 * 512 * 512;       // one 6-layer 512x512 tensor
    u16* encAT  = WTb;                              // [4][6][512*512]
    u16* encW1T = encAT  + 4 * T66;                 // [6][2048*512] ([N=2048][K=512])
    u16* encW2T = encW1T + 6 * (size_t)1048576;     // [6][512*2048]
    u16* decAT  = encW2T + 6 * (size_t)1048576;
    u16* decW1T = decAT  + 4 * T66;
    u16* decW2T = decW1T + 6 * (size_t)1048576;
    u16* projT  = decW2T + 6 * (size_t)1048576;     // [32000][512]

    const dim3 blk(256);

    // ---- weight pre-pass: fp32 [K,N] -> bf16 [N,K] ----
    for (int p = 0; p < 2; ++p) {
        u16* aT  = p ? decAT  : encAT;
        u16* w1T = p ? decW1T : encW1T;
        u16* w2T = p ? decW2T : encW2T;
        wt_k<<<dim3(8, 8, 24), blk, 0, stream>>>(Wt[p][0], Wt[p][1], Wt[p][2], Wt[p][3],
                                                 aT, 512, 512, 6);
        wt_k<<<dim3(32, 8, 6), blk, 0, stream>>>(Wt[p][6], 0, 0, 0, w1T, 512, 2048, 6);
        wt_k<<<dim3(8, 32, 6), blk, 0, stream>>>(Wt[p][8], 0, 0, 0, w2T, 2048, 512, 6);
    }
    wt_k<<<dim3(500, 8, 1), blk, 0, stream>>>(proj_W, 0, 0, 0, projT, 512, 32000, 1);

    auto gemm = [&](const float* A, const u16* B0p, const u16* B1p, const u16* B2p,
                    const float* c0, const float* c1p, const float* c2p,
                    float* O0, float* O1, float* O2,
                    u16* T0, u16* T1, u16* T2,
                    int M, int N, int K, int nz, int act) {
        dim3 g((M / 128) * (N / 128), 1, nz);
        gemm_k<<<g, blk, 0, stream>>>(A, B0p, B1p, B2p, c0, c1p, c2p,
                                      O0, O1, O2, T0, T1, T2, M, N, K, act);
    };
    auto attention = [&](const float* Xq, const float* Xkv, const int* mtok, int causal,
                         const u16* WqT, const u16* WkT, const u16* WvT) {
        if (Xq == Xkv) {
            gemm(Xq, WqT, WkT, WvT, 0, 0, 0, Qb, Kb, 0, 0, 0, Vt, 2048, 512, 512, 3, 0);
        } else {
            gemm(Xq,  WqT, 0, 0, 0, 0, 0, Qb, 0, 0, 0, 0, 0, 2048, 512, 512, 1, 0);
            gemm(Xkv, WkT, WvT, 0, 0, 0, 0, Kb, 0, 0, 0, Vt, 0, 2048, 512, 512, 2, 0);
        }
        scores_k<<<dim3(4, 4, 32), blk, 0, stream>>>(Qb, Kb, Sc);
        softmax_k<<<dim3(4096), blk, 0, stream>>>(Sc, Pm, mtok, causal);
        pv_k<<<dim3(8, 32), blk, 0, stream>>>(Pm, Vt, Atn);
    };

    // ---------------- encoder ----------------
    embed_k<<<B_ * S_, blk, 0, stream>>>(enc_in, emb_enc, Xe);
    for (int l = 0; l < L_; ++l) {
        const u16* WqT = encAT + (size_t)(0 * 6 + l) * 262144;
        const u16* WkT = encAT + (size_t)(1 * 6 + l) * 262144;
        const u16* WvT = encAT + (size_t)(2 * 6 + l) * 262144;
        const u16* WoT = encAT + (size_t)(3 * 6 + l) * 262144;
        const u16* W1T = encW1T + (size_t)l * 1048576;
        const u16* W2T = encW2T + (size_t)l * 1048576;
        const float* g1 = Wt[0][4] + l * D_;
        const float* b1 = Wt[0][5] + l * D_;
        const float* c1 = Wt[0][7] + l * DFF_;
        const float* c2 = Wt[0][9] + l * D_;
        const float* g2 = Wt[0][10] + l * D_;
        const float* b2 = Wt[0][11] + l * D_;

        attention(Xe, Xe, enc_in, 0, WqT, WkT, WvT);
        gemm(Atn, WoT, 0, 0, 0, 0, 0, Fo, 0, 0, 0, 0, 0, 2048, 512, 512, 1, 0);
        ln_k<<<dim3(512), blk, 0, stream>>>(Fo, Xe, g1, b1, Xe);
        gemm(Xe, W1T, 0, 0, c1, 0, 0, Hid, 0, 0, 0, 0, 0, 2048, 2048, 512, 1, 1);
        gemm(Hid, W2T, 0, 0, c2, 0, 0, Fo, 0, 0, 0, 0, 0, 2048, 512, 2048, 1, 0);
        ln_k<<<dim3(512), blk, 0, stream>>>(Fo, Xe, g2, b2, Xe);
    }

    // ---------------- decoder ----------------
    embed_k<<<B_ * S_, blk, 0, stream>>>(dec_in, emb_dec, Xd);
    for (int l = 0; l < L_; ++l) {
        const u16* WqT = decAT + (size_t)(0 * 6 + l) * 262144;
        const u16* WkT = decAT + (size_t)(1 * 6 + l) * 262144;
        const u16* WvT = decAT + (size_t)(2 * 6 + l) * 262144;
        const u16* WoT = decAT + (size_t)(3 * 6 + l) * 262144;
        const u16* W1T = decW1T + (size_t)l * 1048576;
        const u16* W2T = decW2T + (size_t)l * 1048576;
        const float* g1 = Wt[1][4] + l * D_;
        const float* b1 = Wt[1][5] + l * D_;
        const float* c1 = Wt[1][7] + l * DFF_;
        const float* c2 = Wt[1][9] + l * D_;
        const float* g2 = Wt[1][10] + l * D_;
        const float* b2 = Wt[1][11] + l * D_;

        // self-attention (causal + dec pad)
        attention(Xd, Xd, dec_in, 1, WqT, WkT, WvT);
        gemm(Atn, WoT, 0, 0, 0, 0, 0, Fo, 0, 0, 0, 0, 0, 2048, 512, 512, 1, 0);
        ln_k<<<dim3(512), blk, 0, stream>>>(Fo, Xd, g1, b1, Xd);

        // cross-attention (same weights, K/V from enc_out, enc pad mask)
        attention(Xd, Xe, enc_in, 0, WqT, WkT, WvT);
        gemm(Atn, WoT, 0, 0, 0, 0, 0, Fo, 0, 0, 0, 0, 0, 2048, 512, 512, 1, 0);
        ln_k<<<dim3(512), blk, 0, stream>>>(Fo, Xd, g1, b1, Xd);

        // FFN
        gemm(Xd, W1T, 0, 0, c1, 0, 0, Hid, 0, 0, 0, 0, 0, 2048, 2048, 512, 1, 1);
        gemm(Hid, W2T, 0, 0, c2, 0, 0, Fo, 0, 0, 0, 0, 0, 2048, 512, 2048, 1, 0);
        ln_k<<<dim3(512), blk, 0, stream>>>(Fo, Xd, g2, b2, Xd);
    }

    // final projection to vocab (fp32 out)
    gemm(Xd, projT, 0, 0, 0, 0, 0, (float*)d_out, 0, 0, 0, 0, 0, 2048, VD_, 512, 1, 0);
}

// Round 2
// 2250.355 us; speedup vs baseline: 1.7858x; 1.5468x over previous
//
#include <hip/hip_runtime.h>
#include <cstdint>
#include <cstddef>

// ---------------------------------------------------------------------------
// Transformer (enc-dec) forward on MI355X. Round 3:
//  - fused flash attention (QK^T swapped + online softmax + PV in one kernel)
//  - all GEMM A-operands bf16 (activation shadows), staged via global_load_lds
//  - gemm64_k (64x64 tiles, 256 blocks) for the N=512 Wo/W2 GEMMs
//  - cross-attention Q/KV merged into one z=3 dispatch
// Workspace: scratch < 76 MB, bf16 weights at +76 MB (~103 MB used there).
// ---------------------------------------------------------------------------

#define B_   4
#define S_   512
#define D_   512
#define H_   8
#define L_   6
#define DFF_ 2048
#define VD_  32000

typedef unsigned short u16;
typedef short  s16x8  __attribute__((ext_vector_type(8)));
typedef __bf16 bf16x8 __attribute__((ext_vector_type(8)));
typedef float  f32x4  __attribute__((ext_vector_type(4)));

__device__ __forceinline__ u16 f2b(float f) {
    __bf16 h = (__bf16)f; return __builtin_bit_cast(u16, h);
}
__device__ __forceinline__ bf16x8 ld_frag(const u16* p) {
    return __builtin_bit_cast(bf16x8, *(const s16x8*)p);
}
// async 16B global -> LDS (dest = wave-uniform base + lane*16)
__device__ __forceinline__ void gload16(const u16* g, u16* l) {
    __builtin_amdgcn_global_load_lds(
        (const __attribute__((address_space(1))) unsigned int*)(const void*)g,
        (__attribute__((address_space(3))) unsigned int*)(void*)l, 16, 0, 0);
}
__device__ __forceinline__ float wsum(float x) {
#pragma unroll
    for (int m = 32; m > 0; m >>= 1) x += __shfl_xor(x, m, 64);
    return x;
}

// ---------------------------------------------------------------------------
// Weight transpose+convert: in fp32 [K,N] -> out bf16 [N,K].
// ---------------------------------------------------------------------------
__global__ __launch_bounds__(256) void wt_k(const float* __restrict__ in0,
                                            const float* __restrict__ in1,
                                            const float* __restrict__ in2,
                                            const float* __restrict__ in3,
                                            u16* __restrict__ out,
                                            int K, int N, int Lc)
{
    const int z = blockIdx.z;
    const int tsel = z / Lc, l = z % Lc;
    const float* in = tsel == 0 ? in0 : tsel == 1 ? in1 : tsel == 2 ? in2 : in3;
    in += (size_t)l * K * N;
    u16* o = out + (size_t)z * K * N;

    const int n0 = blockIdx.x * 64, k0 = blockIdx.y * 64;
    const int tt = threadIdx.x;
    const int n = tt & 63, kq = tt >> 6;
#pragma unroll
    for (int it = 0; it < 2; ++it) {
        int k8 = kq + it * 4;
        bf16x8 ov;
#pragma unroll
        for (int j = 0; j < 8; ++j)
            ov[j] = (__bf16)in[(size_t)(k0 + k8 * 8 + j) * N + n0 + n];
        *(s16x8*)(o + (size_t)(n0 + n) * K + k0 + k8 * 8) =
            __builtin_bit_cast(s16x8, ov);
    }
}

// ---------------------------------------------------------------------------
// Embedding + positional encoding. fp32 out + bf16 shadow.
// ---------------------------------------------------------------------------
__global__ __launch_bounds__(256) void embed_k(const int* __restrict__ idx,
                                               const float* __restrict__ emb,
                                               float* __restrict__ out,
                                               u16* __restrict__ outb)
{
    int rs = blockIdx.x;          // [0, B*S)
    int s  = rs & (S_ - 1);
    int tok = idx[rs];
#pragma unroll
    for (int i = 0; i < 2; ++i) {
        int d = threadIdx.x + i * 256;
        float e  = emb[(size_t)tok * D_ + d];
        float pe = 0.0f;
        if (s > 0 && d > 0) {
            float ang = (float)s * expf(-(float)d * 0.035977892078031968f); // ln(1e4)/256
            pe = (d & 1) ? cosf(ang) : sinf(ang);
        }
        float x = e + pe;
        out[(size_t)rs * D_ + d]  = x;
        outb[(size_t)rs * D_ + d] = f2b(x);
    }
}

// ---------------------------------------------------------------------------
// GEMM: C[M,N] = act(A @ B + bias). A bf16 [M,K]; B bf16 pre-transposed [N,K].
// Both operands staged via global_load_lds. 128x128 tile, BK=32, 256 thr.
// Per-z: {A, B, bias, out-fp32 | out-bf16 | out-Vt-transpose}.
// Vt mode: T[((row>>9)*8 + col>>6)*64 + (col&63)][row&511] bf16 (V for attn).
// ---------------------------------------------------------------------------
__global__ __launch_bounds__(256) void gemm_k(
    const u16* A0, const u16* A1, const u16* A2,
    const u16* B0, const u16* B1, const u16* B2,
    const float* bias0, const float* bias1, const float* bias2,
    float* Of0, float* Of1, float* Of2,
    u16* Ob0, u16* Ob1, u16* Ob2,
    u16* T0, u16* T1, u16* T2,
    int M, int N, int K, int act)
{
    const u16* A      = blockIdx.z == 0 ? A0 : (blockIdx.z == 1 ? A1 : A2);
    const u16* Bt     = blockIdx.z == 0 ? B0 : (blockIdx.z == 1 ? B1 : B2);
    const float* bias = blockIdx.z == 0 ? bias0 : (blockIdx.z == 1 ? bias1 : bias2);
    float* Of         = blockIdx.z == 0 ? Of0 : (blockIdx.z == 1 ? Of1 : Of2);
    u16* Ob           = blockIdx.z == 0 ? Ob0 : (blockIdx.z == 1 ? Ob1 : Ob2);
    u16* Tt           = blockIdx.z == 0 ? T0 : (blockIdx.z == 1 ? T1 : T2);

    __shared__ u16 As[128 * 32];
    __shared__ u16 Bs[128 * 32];

    const int t = threadIdx.x;
    const int lane = t & 63, wave = t >> 6;
    const int q = lane >> 4, r16 = lane & 15;
    const int wm = (wave & 1) * 64, wn = (wave >> 1) * 64;

    // XCD-chunked bijective swizzle, m-tile fastest
    const int nwg = gridDim.x;
    const int orig = blockIdx.x;
    const int qq = nwg >> 3, rr = nwg & 7;
    const int xcd = orig & 7, loc = orig >> 3;
    const int wg = (xcd < rr ? xcd * (qq + 1) : rr * (qq + 1) + (xcd - rr) * qq) + loc;
    const int mt = M >> 7;
    const int m0 = (wg % mt) * 128, n0 = (wg / mt) * 128;

    f32x4 acc[4][4] = {};

    for (int k0 = 0; k0 < K; k0 += 32) {
#pragma unroll
        for (int r = 0; r < 2; ++r) {                 // A tile 128x32 bf16
            int c = wave * 2 + r;
            gload16(A + (size_t)(m0 + c * 16 + (lane >> 2)) * K + k0 + (lane & 3) * 8,
                    As + c * 512);
        }
#pragma unroll
        for (int r = 0; r < 2; ++r) {                 // B tile 128n x 32k
            int c = wave * 2 + r;
            gload16(Bt + (size_t)(n0 + c * 16 + (lane >> 2)) * K + k0 + (lane & 3) * 8,
                    Bs + c * 512);
        }
        __syncthreads();

        bf16x8 af[4], bf[4];
#pragma unroll
        for (int fm = 0; fm < 4; ++fm)
            af[fm] = ld_frag(As + (wm + fm * 16 + r16) * 32 + q * 8);
#pragma unroll
        for (int fn = 0; fn < 4; ++fn)
            bf[fn] = ld_frag(Bs + (wn + fn * 16 + r16) * 32 + q * 8);
#pragma unroll
        for (int fm = 0; fm < 4; ++fm)
#pragma unroll
            for (int fn = 0; fn < 4; ++fn)
                acc[fm][fn] = __builtin_amdgcn_mfma_f32_16x16x32_bf16(
                    af[fm], bf[fn], acc[fm][fn], 0, 0, 0);
        __syncthreads();
    }

#pragma unroll
    for (int fn = 0; fn < 4; ++fn) {
        int col = n0 + wn + fn * 16 + r16;
        float bv = bias ? bias[col] : 0.0f;
#pragma unroll
        for (int fm = 0; fm < 4; ++fm) {
            int rb = m0 + wm + fm * 16 + q * 4;       // C: col=lane&15, row=quad*4+reg
            if (Tt) {
                u16 w0 = f2b(acc[fm][fn][0] + bv), w1 = f2b(acc[fm][fn][1] + bv);
                u16 w2 = f2b(acc[fm][fn][2] + bv), w3 = f2b(acc[fm][fn][3] + bv);
                uint2 pk;
                pk.x = (unsigned)w0 | ((unsigned)w1 << 16);
                pk.y = (unsigned)w2 | ((unsigned)w3 << 16);
                *(uint2*)(Tt + (((size_t)((rb >> 9) * 8 + (col >> 6)) * 64 + (col & 63)) << 9)
                             + (rb & 511)) = pk;
            } else if (Ob) {
#pragma unroll
                for (int rg = 0; rg < 4; ++rg) {
                    float x = acc[fm][fn][rg] + bv;
                    if (act) x = x >= 0.0f ? x : 0.01f * x;
                    Ob[(size_t)(rb + rg) * N + col] = f2b(x);
                }
            } else {
#pragma unroll
                for (int rg = 0; rg < 4; ++rg) {
                    float x = acc[fm][fn][rg] + bv;
                    if (act) x = x >= 0.0f ? x : 0.01f * x;
                    Of[(size_t)(rb + rg) * N + col] = x;
                }
            }
        }
    }
}

// ---------------------------------------------------------------------------
// Small GEMM: 64x64 tile, BK=32, 256 thr -> 256 blocks for M=2048,N=512.
// A bf16 [M,K], B bf16 [N,K], out fp32 (+bias). No activation.
// ---------------------------------------------------------------------------
__global__ __launch_bounds__(256) void gemm64_k(
    const u16* A, const u16* Bt, const float* bias, float* O,
    int M, int N, int K)
{
    __shared__ u16 As[64 * 32];
    __shared__ u16 Bs[64 * 32];

    const int t = threadIdx.x;
    const int lane = t & 63, wave = t >> 6;
    const int q = lane >> 4, r16 = lane & 15;
    const int wm = (wave & 1) * 32, wn = (wave >> 1) * 32;

    const int nwg = gridDim.x;
    const int orig = blockIdx.x;
    const int qq = nwg >> 3, rr = nwg & 7;
    const int xcd = orig & 7, loc = orig >> 3;
    const int wg = (xcd < rr ? xcd * (qq + 1) : rr * (qq + 1) + (xcd - rr) * qq) + loc;
    const int mt = M >> 6;
    const int m0 = (wg % mt) * 64, n0 = (wg / mt) * 64;

    f32x4 acc[2][2] = {};

    for (int k0 = 0; k0 < K; k0 += 32) {
        // A tile 64x32 (4 chunks of 16 rows), chunk = wave
        gload16(A + (size_t)(m0 + wave * 16 + (lane >> 2)) * K + k0 + (lane & 3) * 8,
                As + wave * 512);
        gload16(Bt + (size_t)(n0 + wave * 16 + (lane >> 2)) * K + k0 + (lane & 3) * 8,
                Bs + wave * 512);
        __syncthreads();

        bf16x8 af[2], bf[2];
#pragma unroll
        for (int fm = 0; fm < 2; ++fm)
            af[fm] = ld_frag(As + (wm + fm * 16 + r16) * 32 + q * 8);
#pragma unroll
        for (int fn = 0; fn < 2; ++fn)
            bf[fn] = ld_frag(Bs + (wn + fn * 16 + r16) * 32 + q * 8);
#pragma unroll
        for (int fm = 0; fm < 2; ++fm)
#pragma unroll
            for (int fn = 0; fn < 2; ++fn)
                acc[fm][fn] = __builtin_amdgcn_mfma_f32_16x16x32_bf16(
                    af[fm], bf[fn], acc[fm][fn], 0, 0, 0);
        __syncthreads();
    }

#pragma unroll
    for (int fn = 0; fn < 2; ++fn) {
        int col = n0 + wn + fn * 16 + r16;
        float bv = bias ? bias[col] : 0.0f;
#pragma unroll
        for (int fm = 0; fm < 2; ++fm) {
            int rb = m0 + wm + fm * 16 + q * 4;
#pragma unroll
            for (int rg = 0; rg < 4; ++rg)
                O[(size_t)(rb + rg) * N + col] = acc[fm][fn][rg] + bv;
        }
    }
}

// ---------------------------------------------------------------------------
// Fused flash attention. grid (S/64, B*H), 256 thr.
// Qb,Kb bf16 [B*S][512] (head at h*64); Vt bf16 [bh][64][512].
// Swapped QK^T: S^T = mfma(K, Q) so softmax is (mostly) in-lane.
// Masked entries = 1e-9 before softmax (faithful). Online softmax over
// 4 k-tiles of 128. P -> LDS bf16 -> PV = mfma(Vt, P). Out bf16 [B*S][512].
// ---------------------------------------------------------------------------
__global__ __launch_bounds__(256) void attn_k(const u16* __restrict__ Qb,
                                              const u16* __restrict__ Kb,
                                              const u16* __restrict__ Vt,
                                              u16* __restrict__ Ob,
                                              const int* __restrict__ tok,
                                              int causal)
{
    __shared__ u16 Qs[64 * 72];    // [q][dk]
    __shared__ u16 Ks[128 * 72];   // [k][dk]
    __shared__ u16 Vs[64 * 136];   // [d][k]
    __shared__ u16 Ps[64 * 136];   // [q][k]  (P, bf16)
    __shared__ int tokS[128];

    const int t = threadIdx.x;
    const int lane = t & 63, wave = t >> 6;
    const int q = lane >> 4, r16 = lane & 15;
    const int m0 = blockIdx.x * 64;
    const int bh = blockIdx.y, b = bh >> 3, h = bh & 7;
    const int qi = m0 + wave * 16 + r16;          // this lane's q-row (global in seq)
    const int* kb = tok + b * S_;

    // stage Q (64 x 64)
#pragma unroll
    for (int r = 0; r < 2; ++r) {
        int u = t + r * 256;
        int row = u >> 3, c8 = u & 7;
        *(uint4*)(Qs + row * 72 + c8 * 8) =
            *(const uint4*)(Qb + ((size_t)(b * S_ + m0 + row)) * D_ + h * 64 + c8 * 8);
    }

    float mrun = -3.0e38f, lrun = 0.0f;
    f32x4 o[4] = {};
    const f32x4 zer = {};

    for (int kt = 0; kt < 4; ++kt) {
        const int k0 = kt * 128;
        // stage K (128 x 64), V (64 d x 128 k), tok
#pragma unroll
        for (int r = 0; r < 4; ++r) {
            int u = t + r * 256;
            int row = u >> 3, c8 = u & 7;
            *(uint4*)(Ks + row * 72 + c8 * 8) =
                *(const uint4*)(Kb + ((size_t)(b * S_ + k0 + row)) * D_ + h * 64 + c8 * 8);
        }
#pragma unroll
        for (int r = 0; r < 4; ++r) {
            int u = t + r * 256;
            int d = u >> 4, c = u & 15;
            *(uint4*)(Vs + d * 136 + c * 8) =
                *(const uint4*)(Vt + ((size_t)bh * 64 + d) * S_ + k0 + c * 8);
        }
        if (t < 128) tokS[t] = kb[k0 + t];
        __syncthreads();

        // S^T[k_local][q_local]: per wave, q-cols [wave*16, wave*16+16)
        bf16x8 qf0 = ld_frag(Qs + (wave * 16 + r16) * 72 + 0  + q * 8);
        bf16x8 qf1 = ld_frag(Qs + (wave * 16 + r16) * 72 + 32 + q * 8);
        f32x4 s[8];
#pragma unroll
        for (int km = 0; km < 8; ++km) {
            s[km] = zer;
            s[km] = __builtin_amdgcn_mfma_f32_16x16x32_bf16(
                ld_frag(Ks + (km * 16 + r16) * 72 + 0 + q * 8), qf0, s[km], 0, 0, 0);
            s[km] = __builtin_amdgcn_mfma_f32_16x16x32_bf16(
                ld_frag(Ks + (km * 16 + r16) * 72 + 32 + q * 8), qf1, s[km], 0, 0, 0);
        }

        // mask + scale; tile max (in-lane 32 vals + xor 16/32 across q-groups)
        float tmax = -3.0e38f;
#pragma unroll
        for (int km = 0; km < 8; ++km)
#pragma unroll
            for (int rg = 0; rg < 4; ++rg) {
                int kl = km * 16 + q * 4 + rg;
                bool msk = (tokS[kl] == 0) || (causal && (k0 + kl > qi));
                float x = msk ? 1e-9f : s[km][rg] * 0.125f;
                s[km][rg] = x;
                tmax = fmaxf(tmax, x);
            }
        tmax = fmaxf(tmax, __shfl_xor(tmax, 16, 64));
        tmax = fmaxf(tmax, __shfl_xor(tmax, 32, 64));
        float mnew = fmaxf(mrun, tmax);
        float sc = __expf(mrun - mnew);
        float tsum = 0.0f;
#pragma unroll
        for (int km = 0; km < 8; ++km)
#pragma unroll
            for (int rg = 0; rg < 4; ++rg) {
                float p = __expf(s[km][rg] - mnew);
                s[km][rg] = p;
                tsum += p;
            }
        tsum += __shfl_xor(tsum, 16, 64);
        tsum += __shfl_xor(tsum, 32, 64);
        lrun = lrun * sc + tsum;
        mrun = mnew;
#pragma unroll
        for (int fm = 0; fm < 4; ++fm)
#pragma unroll
            for (int rg = 0; rg < 4; ++rg) o[fm][rg] *= sc;

        // write P (bf16, 8B packed: 4 consecutive k per store)
#pragma unroll
        for (int km = 0; km < 8; ++km) {
            uint2 pk;
            pk.x = (unsigned)f2b(s[km][0]) | ((unsigned)f2b(s[km][1]) << 16);
            pk.y = (unsigned)f2b(s[km][2]) | ((unsigned)f2b(s[km][3]) << 16);
            *(uint2*)(Ps + (wave * 16 + r16) * 136 + km * 16 + q * 4) = pk;
        }
        __syncthreads();

        // PV: O^T[d][q] += sum_k Vt[d][k] P[q][k]
        bf16x8 pf[4];
#pragma unroll
        for (int ks = 0; ks < 4; ++ks)
            pf[ks] = ld_frag(Ps + (wave * 16 + r16) * 136 + ks * 32 + q * 8);
#pragma unroll
        for (int fm = 0; fm < 4; ++fm)
#pragma unroll
            for (int ks = 0; ks < 4; ++ks)
                o[fm] = __builtin_amdgcn_mfma_f32_16x16x32_bf16(
                    ld_frag(Vs + (fm * 16 + r16) * 136 + ks * 32 + q * 8),
                    pf[ks], o[fm], 0, 0, 0);
        __syncthreads();
    }

    float inv = 1.0f / lrun;
#pragma unroll
    for (int fm = 0; fm < 4; ++fm) {
        uint2 pk;
        pk.x = (unsigned)f2b(o[fm][0] * inv) | ((unsigned)f2b(o[fm][1] * inv) << 16);
        pk.y = (unsigned)f2b(o[fm][2] * inv) | ((unsigned)f2b(o[fm][3] * inv) << 16);
        *(uint2*)(Ob + ((size_t)(b * S_ + m0 + wave * 16 + r16)) * D_
                     + h * 64 + fm * 16 + q * 4) = pk;
    }
}

// ---------------------------------------------------------------------------
// LayerNorm: out = LN(x32 + resid) * g + b. fp32 out + bf16 shadow.
// ---------------------------------------------------------------------------
__global__ __launch_bounds__(256) void ln_k(const float* __restrict__ X32,
                                            const float* resid,
                                            const float* __restrict__ g,
                                            const float* __restrict__ be,
                                            float* out, u16* outb)
{
    const int wave = threadIdx.x >> 6, lane = threadIdx.x & 63;
    const int row = blockIdx.x * 4 + wave;
    const float* xr = X32 + (size_t)row * D_;
    const float* rr = resid + (size_t)row * D_;

    float v[8];
    float s = 0.0f;
#pragma unroll
    for (int i = 0; i < 8; ++i) {
        v[i] = xr[i * 64 + lane] + rr[i * 64 + lane];
        s += v[i];
    }
    s = wsum(s);
    float mean = s * (1.0f / D_);
    float s2 = 0.0f;
#pragma unroll
    for (int i = 0; i < 8; ++i) { float d = v[i] - mean; s2 += d * d; }
    s2 = wsum(s2);
    float inv = rsqrtf(s2 * (1.0f / D_) + 1e-6f);
#pragma unroll
    for (int i = 0; i < 8; ++i) {
        int c = i * 64 + lane;
        float y = (v[i] - mean) * inv * g[c] + be[c];
        out[(size_t)row * D_ + c]  = y;
        outb[(size_t)row * D_ + c] = f2b(y);
    }
}

// ---------------------------------------------------------------------------
// Host-side orchestration
// ---------------------------------------------------------------------------
extern "C" void kernel_launch(void* const* d_in, const int* in_sizes, int n_in,
                              void* d_out, int out_size, void* d_ws, size_t ws_size,
                              hipStream_t stream)
{
    (void)in_sizes; (void)n_in; (void)out_size; (void)ws_size;

    const int*   enc_in  = (const int*)d_in[0];
    const int*   dec_in  = (const int*)d_in[1];
    const float* emb_enc = (const float*)d_in[2];
    const float* emb_dec = (const float*)d_in[3];
    const float* proj_W  = (const float*)d_in[4];
    const float* Wt[2][12];
    for (int p = 0; p < 2; ++p)
        for (int j = 0; j < 12; ++j)
            Wt[p][j] = (const float*)d_in[5 + p * 12 + j];

    char* ws = (char*)d_ws;
    const size_t MB = 1024 * 1024;
    float* Xe   = (float*)(ws + 0 * MB);    // [2048,512] f32 (enc act / enc_out)
    float* Xd   = (float*)(ws + 4 * MB);    // [2048,512] f32 (dec act)
    float* Fo   = (float*)(ws + 8 * MB);    // pre-LN matmul out f32
    u16*   HidB = (u16*)  (ws + 12 * MB);   // FFN hidden bf16 [2048,2048], 8 MB
    u16*   Qb   = (u16*)  (ws + 20 * MB);   // Q bf16 [2048,512], 2 MB
    u16*   Kb   = (u16*)  (ws + 22 * MB);   // K bf16
    u16*   Vt   = (u16*)  (ws + 24 * MB);   // V transposed bf16 [32][64][512]
    u16*   AtnB = (u16*)  (ws + 26 * MB);   // attention out bf16 [2048,512]
    u16*   Xeb  = (u16*)  (ws + 28 * MB);   // enc act bf16 shadow
    u16*   Xdb  = (u16*)  (ws + 30 * MB);   // dec act bf16 shadow

    // bf16 transposed weights: 76 MB ..
    u16* WTb = (u16*)(ws + 76 * MB);
    const size_t T66 = (size_t)6 * 512 * 512;
    u16* encAT  = WTb;                              // [4][6][512*512]
    u16* encW1T = encAT  + 4 * T66;                 // [6][2048*512]
    u16* encW2T = encW1T + 6 * (size_t)1048576;     // [6][512*2048]
    u16* decAT  = encW2T + 6 * (size_t)1048576;
    u16* decW1T = decAT  + 4 * T66;
    u16* decW2T = decW1T + 6 * (size_t)1048576;
    u16* projT  = decW2T + 6 * (size_t)1048576;     // [32000][512]

    const dim3 blk(256);

    // ---- weight pre-pass: fp32 [K,N] -> bf16 [N,K] ----
    for (int p = 0; p < 2; ++p) {
        u16* aT  = p ? decAT  : encAT;
        u16* w1T = p ? decW1T : encW1T;
        u16* w2T = p ? decW2T : encW2T;
        wt_k<<<dim3(8, 8, 24), blk, 0, stream>>>(Wt[p][0], Wt[p][1], Wt[p][2], Wt[p][3],
                                                 aT, 512, 512, 6);
        wt_k<<<dim3(32, 8, 6), blk, 0, stream>>>(Wt[p][6], 0, 0, 0, w1T, 512, 2048, 6);
        wt_k<<<dim3(8, 32, 6), blk, 0, stream>>>(Wt[p][8], 0, 0, 0, w2T, 2048, 512, 6);
    }
    wt_k<<<dim3(500, 8, 1), blk, 0, stream>>>(proj_W, 0, 0, 0, projT, 512, 32000, 1);

    // full-size GEMM (per-z A/B/out). Modes: Of fp32, Ob bf16, Tt V-transpose.
    auto gemm = [&](const u16* A0p, const u16* A1p, const u16* A2p,
                    const u16* B0p, const u16* B1p, const u16* B2p,
                    const float* c0, const float* c1p, const float* c2p,
                    float* Of0, float* Of1, float* Of2,
                    u16* Ob0, u16* Ob1, u16* Ob2,
                    u16* T0, u16* T1, u16* T2,
                    int M, int N, int K, int nz, int act) {
        dim3 g((M / 128) * (N / 128), 1, nz);
        gemm_k<<<g, blk, 0, stream>>>(A0p, A1p, A2p, B0p, B1p, B2p, c0, c1p, c2p,
                                      Of0, Of1, Of2, Ob0, Ob1, Ob2, T0, T1, T2,
                                      M, N, K, act);
    };
    auto gemm64 = [&](const u16* A, const u16* Bp, const float* c, float* O,
                      int M, int N, int K) {
        dim3 g((M / 64) * (N / 64), 1, 1);
        gemm64_k<<<g, blk, 0, stream>>>(A, Bp, c, O, M, N, K);
    };
    auto attention = [&](const u16* XqB, const u16* XkvB, const int* mtok, int causal,
                         const u16* WqT, const u16* WkT, const u16* WvT) {
        // QKV (q from XqB; k,v from XkvB) in one z=3 dispatch
        gemm(XqB, XkvB, XkvB, WqT, WkT, WvT, 0, 0, 0,
             0, 0, 0, Qb, Kb, 0, 0, 0, Vt, 2048, 512, 512, 3, 0);
        attn_k<<<dim3(8, 32), blk, 0, stream>>>(Qb, Kb, Vt, AtnB, mtok, causal);
    };

    // ---------------- encoder ----------------
    embed_k<<<B_ * S_, blk, 0, stream>>>(enc_in, emb_enc, Xe, Xeb);
    for (int l = 0; l < L_; ++l) {
        const u16* WqT = encAT + (size_t)(0 * 6 + l) * 262144;
        const u16* WkT = encAT + (size_t)(1 * 6 + l) * 262144;
        const u16* WvT = encAT + (size_t)(2 * 6 + l) * 262144;
        const u16* WoT = encAT + (size_t)(3 * 6 + l) * 262144;
        const u16* W1T = encW1T + (size_t)l * 1048576;
        const u16* W2T = encW2T + (size_t)l * 1048576;
        const float* g1 = Wt[0][4] + l * D_;
        const float* b1 = Wt[0][5] + l * D_;
        const float* c1 = Wt[0][7] + l * DFF_;
        const float* c2 = Wt[0][9] + l * D_;
        const float* g2 = Wt[0][10] + l * D_;
        const float* b2 = Wt[0][11] + l * D_;

        attention(Xeb, Xeb, enc_in, 0, WqT, WkT, WvT);
        gemm64(AtnB, WoT, 0, Fo, 2048, 512, 512);
        ln_k<<<dim3(512), blk, 0, stream>>>(Fo, Xe, g1, b1, Xe, Xeb);
        gemm(Xeb, 0, 0, W1T, 0, 0, c1, 0, 0,
             0, 0, 0, HidB, 0, 0, 0, 0, 0, 2048, 2048, 512, 1, 1);
        gemm64(HidB, W2T, c2, Fo, 2048, 512, 2048);
        ln_k<<<dim3(512), blk, 0, stream>>>(Fo, Xe, g2, b2, Xe, Xeb);
    }

    // ---------------- decoder ----------------
    embed_k<<<B_ * S_, blk, 0, stream>>>(dec_in, emb_dec, Xd, Xdb);
    for (int l = 0; l < L_; ++l) {
        const u16* WqT = decAT + (size_t)(0 * 6 + l) * 262144;
        const u16* WkT = decAT + (size_t)(1 * 6 + l) * 262144;
        const u16* WvT = decAT + (size_t)(2 * 6 + l) * 262144;
        const u16* WoT = decAT + (size_t)(3 * 6 + l) * 262144;
        const u16* W1T = decW1T + (size_t)l * 1048576;
        const u16* W2T = decW2T + (size_t)l * 1048576;
        const float* g1 = Wt[1][4] + l * D_;
        const float* b1 = Wt[1][5] + l * D_;
        const float* c1 = Wt[1][7] + l * DFF_;
        const float* c2 = Wt[1][9] + l * D_;
        const float* g2 = Wt[1][10] + l * D_;
        const float* b2 = Wt[1][11] + l * D_;

        // self-attention (causal + dec pad)
        attention(Xdb, Xdb, dec_in, 1, WqT, WkT, WvT);
        gemm64(AtnB, WoT, 0, Fo, 2048, 512, 512);
        ln_k<<<dim3(512), blk, 0, stream>>>(Fo, Xd, g1, b1, Xd, Xdb);

        // cross-attention (same weights, K/V from enc_out, enc pad mask)
        attention(Xdb, Xeb, enc_in, 0, WqT, WkT, WvT);
        gemm64(AtnB, WoT, 0, Fo, 2048, 512, 512);
        ln_k<<<dim3(512), blk, 0, stream>>>(Fo, Xd, g1, b1, Xd, Xdb);

        // FFN
        gemm(Xdb, 0, 0, W1T, 0, 0, c1, 0, 0,
             0, 0, 0, HidB, 0, 0, 0, 0, 0, 2048, 2048, 512, 1, 1);
        gemm64(HidB, W2T, c2, Fo, 2048, 512, 2048);
        ln_k<<<dim3(512), blk, 0, stream>>>(Fo, Xd, g2, b2, Xd, Xdb);
    }

    // final projection to vocab (fp32 out)
    gemm(Xdb, 0, 0, projT, 0, 0, 0, 0, 0,
         (float*)d_out, 0, 0, 0, 0, 0, 0, 0, 0, 2048, VD_, 512, 1, 0);
}

// Round 3
// 2057.406 us; speedup vs baseline: 1.9533x; 1.0938x over previous
//
#include <hip/hip_runtime.h>
#include <cstdint>
#include <cstddef>

// ---------------------------------------------------------------------------
// Transformer (enc-dec) forward on MI355X. Round 4:
//  - attn_k v2: barrier-free (Q in regs, K/V fragments direct from global/L2,
//    P wave-private in LDS), 19 KB LDS
//  - gemm64z_k: 64x64-tile GEMM, per-z operand tuples, lda/ldb decoupled from
//    K -> QKV z=3 (768 blk), W1 (1024 blk), Wo/W2 split-K=2 via z (512 blk)
//  - ln_k: sums up to 2 partials + residual + col-bias, then LN (fuses split-K
//    reduction and W2's c2 bias)
//  - gemm_k 128x128 retained for the vocab projection only
// ---------------------------------------------------------------------------

#define B_   4
#define S_   512
#define D_   512
#define H_   8
#define L_   6
#define DFF_ 2048
#define VD_  32000

typedef unsigned short u16;
typedef short  s16x8  __attribute__((ext_vector_type(8)));
typedef __bf16 bf16x8 __attribute__((ext_vector_type(8)));
typedef float  f32x4  __attribute__((ext_vector_type(4)));

__device__ __forceinline__ u16 f2b(float f) {
    __bf16 h = (__bf16)f; return __builtin_bit_cast(u16, h);
}
__device__ __forceinline__ bf16x8 ld_frag(const u16* p) {
    return __builtin_bit_cast(bf16x8, *(const s16x8*)p);
}
// async 16B global -> LDS (dest = wave-uniform base + lane*16)
__device__ __forceinline__ void gload16(const u16* g, u16* l) {
    __builtin_amdgcn_global_load_lds(
        (const __attribute__((address_space(1))) unsigned int*)(const void*)g,
        (__attribute__((address_space(3))) unsigned int*)(void*)l, 16, 0, 0);
}
__device__ __forceinline__ float wsum(float x) {
#pragma unroll
    for (int m = 32; m > 0; m >>= 1) x += __shfl_xor(x, m, 64);
    return x;
}

// ---------------------------------------------------------------------------
// Weight transpose+convert: in fp32 [K,N] -> out bf16 [N,K].
// ---------------------------------------------------------------------------
__global__ __launch_bounds__(256) void wt_k(const float* __restrict__ in0,
                                            const float* __restrict__ in1,
                                            const float* __restrict__ in2,
                                            const float* __restrict__ in3,
                                            u16* __restrict__ out,
                                            int K, int N, int Lc)
{
    const int z = blockIdx.z;
    const int tsel = z / Lc, l = z % Lc;
    const float* in = tsel == 0 ? in0 : tsel == 1 ? in1 : tsel == 2 ? in2 : in3;
    in += (size_t)l * K * N;
    u16* o = out + (size_t)z * K * N;

    const int n0 = blockIdx.x * 64, k0 = blockIdx.y * 64;
    const int tt = threadIdx.x;
    const int n = tt & 63, kq = tt >> 6;
#pragma unroll
    for (int it = 0; it < 2; ++it) {
        int k8 = kq + it * 4;
        bf16x8 ov;
#pragma unroll
        for (int j = 0; j < 8; ++j)
            ov[j] = (__bf16)in[(size_t)(k0 + k8 * 8 + j) * N + n0 + n];
        *(s16x8*)(o + (size_t)(n0 + n) * K + k0 + k8 * 8) =
            __builtin_bit_cast(s16x8, ov);
    }
}

// ---------------------------------------------------------------------------
// Embedding + positional encoding. fp32 out + bf16 shadow.
// ---------------------------------------------------------------------------
__global__ __launch_bounds__(256) void embed_k(const int* __restrict__ idx,
                                               const float* __restrict__ emb,
                                               float* __restrict__ out,
                                               u16* __restrict__ outb)
{
    int rs = blockIdx.x;          // [0, B*S)
    int s  = rs & (S_ - 1);
    int tok = idx[rs];
#pragma unroll
    for (int i = 0; i < 2; ++i) {
        int d = threadIdx.x + i * 256;
        float e  = emb[(size_t)tok * D_ + d];
        float pe = 0.0f;
        if (s > 0 && d > 0) {
            float ang = (float)s * expf(-(float)d * 0.035977892078031968f); // ln(1e4)/256
            pe = (d & 1) ? cosf(ang) : sinf(ang);
        }
        float x = e + pe;
        out[(size_t)rs * D_ + d]  = x;
        outb[(size_t)rs * D_ + d] = f2b(x);
    }
}

// ---------------------------------------------------------------------------
// Big GEMM (proj): C[M,N] = A @ B. A bf16 [M,K]; B bf16 [N,K]. 128x128 tile.
// ---------------------------------------------------------------------------
__global__ __launch_bounds__(256) void gemm_k(
    const u16* __restrict__ A, const u16* __restrict__ Bt,
    float* __restrict__ Of, int M, int N, int K)
{
    __shared__ u16 As[128 * 32];
    __shared__ u16 Bs[128 * 32];

    const int t = threadIdx.x;
    const int lane = t & 63, wave = t >> 6;
    const int q = lane >> 4, r16 = lane & 15;
    const int wm = (wave & 1) * 64, wn = (wave >> 1) * 64;

    const int nwg = gridDim.x;
    const int orig = blockIdx.x;
    const int qq = nwg >> 3, rr = nwg & 7;
    const int xcd = orig & 7, loc = orig >> 3;
    const int wg = (xcd < rr ? xcd * (qq + 1) : rr * (qq + 1) + (xcd - rr) * qq) + loc;
    const int mt = M >> 7;
    const int m0 = (wg % mt) * 128, n0 = (wg / mt) * 128;

    f32x4 acc[4][4] = {};

    for (int k0 = 0; k0 < K; k0 += 32) {
#pragma unroll
        for (int r = 0; r < 2; ++r) {
            int c = wave * 2 + r;
            gload16(A + (size_t)(m0 + c * 16 + (lane >> 2)) * K + k0 + (lane & 3) * 8,
                    As + c * 512);
        }
#pragma unroll
        for (int r = 0; r < 2; ++r) {
            int c = wave * 2 + r;
            gload16(Bt + (size_t)(n0 + c * 16 + (lane >> 2)) * K + k0 + (lane & 3) * 8,
                    Bs + c * 512);
        }
        __syncthreads();

        bf16x8 af[4], bf[4];
#pragma unroll
        for (int fm = 0; fm < 4; ++fm)
            af[fm] = ld_frag(As + (wm + fm * 16 + r16) * 32 + q * 8);
#pragma unroll
        for (int fn = 0; fn < 4; ++fn)
            bf[fn] = ld_frag(Bs + (wn + fn * 16 + r16) * 32 + q * 8);
#pragma unroll
        for (int fm = 0; fm < 4; ++fm)
#pragma unroll
            for (int fn = 0; fn < 4; ++fn)
                acc[fm][fn] = __builtin_amdgcn_mfma_f32_16x16x32_bf16(
                    af[fm], bf[fn], acc[fm][fn], 0, 0, 0);
        __syncthreads();
    }

#pragma unroll
    for (int fn = 0; fn < 4; ++fn) {
        int col = n0 + wn + fn * 16 + r16;
#pragma unroll
        for (int fm = 0; fm < 4; ++fm) {
            int rb = m0 + wm + fm * 16 + q * 4;
#pragma unroll
            for (int rg = 0; rg < 4; ++rg)
                Of[(size_t)(rb + rg) * N + col] = acc[fm][fn][rg];
        }
    }
}

// ---------------------------------------------------------------------------
// Small GEMM: 64x64 tile, BK=32, 256 thr. Per-z tuples {A, B, bias, out-mode}.
// lda/ldb decoupled from Kred (enables split-K via pointer offset).
// Out modes (first non-null wins): Tt (V-transpose bf16), Ob (bf16, +act),
// Of (fp32). act = leaky_relu 0.01.
// ---------------------------------------------------------------------------
__global__ __launch_bounds__(256) void gemm64z_k(
    const u16* A0, const u16* A1, const u16* A2,
    const u16* B0, const u16* B1, const u16* B2,
    const float* bias0, const float* bias1, const float* bias2,
    float* Of0, float* Of1, float* Of2,
    u16* Ob0, u16* Ob1, u16* Ob2,
    u16* T0, u16* T1, u16* T2,
    int M, int N, int Kred, int lda, int ldb, int act)
{
    const int z = blockIdx.z;
    const u16* A      = z == 0 ? A0 : (z == 1 ? A1 : A2);
    const u16* Bt     = z == 0 ? B0 : (z == 1 ? B1 : B2);
    const float* bias = z == 0 ? bias0 : (z == 1 ? bias1 : bias2);
    float* Of         = z == 0 ? Of0 : (z == 1 ? Of1 : Of2);
    u16* Ob           = z == 0 ? Ob0 : (z == 1 ? Ob1 : Ob2);
    u16* Tt           = z == 0 ? T0 : (z == 1 ? T1 : T2);

    __shared__ u16 As[64 * 32];
    __shared__ u16 Bs[64 * 32];

    const int t = threadIdx.x;
    const int lane = t & 63, wave = t >> 6;
    const int q = lane >> 4, r16 = lane & 15;
    const int wm = (wave & 1) * 32, wn = (wave >> 1) * 32;

    const int nwg = gridDim.x;
    const int orig = blockIdx.x;
    const int qq = nwg >> 3, rr = nwg & 7;
    const int xcd = orig & 7, loc = orig >> 3;
    const int wg = (xcd < rr ? xcd * (qq + 1) : rr * (qq + 1) + (xcd - rr) * qq) + loc;
    const int mt = M >> 6;
    const int m0 = (wg % mt) * 64, n0 = (wg / mt) * 64;

    f32x4 acc[2][2] = {};

    for (int k0 = 0; k0 < Kred; k0 += 32) {
        gload16(A + (size_t)(m0 + wave * 16 + (lane >> 2)) * lda + k0 + (lane & 3) * 8,
                As + wave * 512);
        gload16(Bt + (size_t)(n0 + wave * 16 + (lane >> 2)) * ldb + k0 + (lane & 3) * 8,
                Bs + wave * 512);
        __syncthreads();

        bf16x8 af[2], bf[2];
#pragma unroll
        for (int fm = 0; fm < 2; ++fm)
            af[fm] = ld_frag(As + (wm + fm * 16 + r16) * 32 + q * 8);
#pragma unroll
        for (int fn = 0; fn < 2; ++fn)
            bf[fn] = ld_frag(Bs + (wn + fn * 16 + r16) * 32 + q * 8);
#pragma unroll
        for (int fm = 0; fm < 2; ++fm)
#pragma unroll
            for (int fn = 0; fn < 2; ++fn)
                acc[fm][fn] = __builtin_amdgcn_mfma_f32_16x16x32_bf16(
                    af[fm], bf[fn], acc[fm][fn], 0, 0, 0);
        __syncthreads();
    }

#pragma unroll
    for (int fn = 0; fn < 2; ++fn) {
        int col = n0 + wn + fn * 16 + r16;
        float bv = bias ? bias[col] : 0.0f;
#pragma unroll
        for (int fm = 0; fm < 2; ++fm) {
            int rb = m0 + wm + fm * 16 + q * 4;   // C: col=lane&15, row=quad*4+reg
            if (Tt) {
                u16 w0 = f2b(acc[fm][fn][0] + bv), w1 = f2b(acc[fm][fn][1] + bv);
                u16 w2 = f2b(acc[fm][fn][2] + bv), w3 = f2b(acc[fm][fn][3] + bv);
                uint2 pk;
                pk.x = (unsigned)w0 | ((unsigned)w1 << 16);
                pk.y = (unsigned)w2 | ((unsigned)w3 << 16);
                *(uint2*)(Tt + (((size_t)((rb >> 9) * 8 + (col >> 6)) * 64 + (col & 63)) << 9)
                             + (rb & 511)) = pk;
            } else if (Ob) {
#pragma unroll
                for (int rg = 0; rg < 4; ++rg) {
                    float x = acc[fm][fn][rg] + bv;
                    if (act) x = x >= 0.0f ? x : 0.01f * x;
                    Ob[(size_t)(rb + rg) * N + col] = f2b(x);
                }
            } else {
#pragma unroll
                for (int rg = 0; rg < 4; ++rg)
                    Of[(size_t)(rb + rg) * N + col] = acc[fm][fn][rg] + bv;
            }
        }
    }
}

// ---------------------------------------------------------------------------
// Fused flash attention v2 (barrier-free main loop). grid (S/64, B*H), 256 thr.
// Qb,Kb bf16 [B*S][512] (head at h*64); Vt bf16 [bh][64][512].
// Q in registers; K/V fragments read directly from global (L2/L3-resident).
// Swapped QK^T: lane holds S^T[k=km*16+q*4+rg][qcol=wave*16+r16].
// P round-trips through wave-private LDS rows -> no __syncthreads needed.
// Masked entries = 1e-9 before softmax (faithful). Out bf16 [B*S][512].
// ---------------------------------------------------------------------------
__global__ __launch_bounds__(256) void attn_k(const u16* __restrict__ Qb,
                                              const u16* __restrict__ Kb,
                                              const u16* __restrict__ Vt,
                                              u16* __restrict__ Ob,
                                              const int* __restrict__ tok,
                                              int causal)
{
    __shared__ u16 Ps[64 * 136];   // [q][k] bf16, rows wave-private
    __shared__ int tokS[512];

    const int t = threadIdx.x;
    const int lane = t & 63, wave = t >> 6;
    const int q = lane >> 4, r16 = lane & 15;
    const int m0 = blockIdx.x * 64;
    const int bh = blockIdx.y, b = bh >> 3, h = bh & 7;
    const int qi = m0 + wave * 16 + r16;          // this lane's q-row
    const int* kb = tok + b * S_;

    tokS[t] = kb[t];
    tokS[t + 256] = kb[t + 256];
    __syncthreads();

    // Q fragments in registers
    const u16* qp = Qb + ((size_t)(b * S_ + m0 + wave * 16 + r16)) * D_ + h * 64 + q * 8;
    const bf16x8 qf0 = ld_frag(qp), qf1 = ld_frag(qp + 32);

    const u16* kbase = Kb + ((size_t)b * S_) * D_ + h * 64 + q * 8;
    const u16* vbase = Vt + ((size_t)bh * 64 + r16) * S_ + q * 8;
    u16* prow = Ps + (wave * 16 + r16) * 136;

    float mrun = -3.0e38f, lrun = 0.0f;
    f32x4 o[4] = {};
    const f32x4 zer = {};

    for (int kt = 0; kt < 4; ++kt) {
        const int k0 = kt * 128;

        // QK^T: fragments straight from global
        f32x4 s[8];
#pragma unroll
        for (int km = 0; km < 8; ++km) {
            const u16* kp = kbase + (size_t)(k0 + km * 16 + r16) * D_;
            s[km] = zer;
            s[km] = __builtin_amdgcn_mfma_f32_16x16x32_bf16(ld_frag(kp), qf0, s[km], 0, 0, 0);
            s[km] = __builtin_amdgcn_mfma_f32_16x16x32_bf16(ld_frag(kp + 32), qf1, s[km], 0, 0, 0);
        }

        // mask + scale; tile max across the 4 q-groups holding this q-col
        float tmax = -3.0e38f;
#pragma unroll
        for (int km = 0; km < 8; ++km)
#pragma unroll
            for (int rg = 0; rg < 4; ++rg) {
                int kl = km * 16 + q * 4 + rg;
                bool msk = (tokS[k0 + kl] == 0) || (causal && (k0 + kl > qi));
                float x = msk ? 1e-9f : s[km][rg] * 0.125f;
                s[km][rg] = x;
                tmax = fmaxf(tmax, x);
            }
        tmax = fmaxf(tmax, __shfl_xor(tmax, 16, 64));
        tmax = fmaxf(tmax, __shfl_xor(tmax, 32, 64));
        float mnew = fmaxf(mrun, tmax);
        float sc = __expf(mrun - mnew);
        float tsum = 0.0f;
#pragma unroll
        for (int km = 0; km < 8; ++km)
#pragma unroll
            for (int rg = 0; rg < 4; ++rg) {
                float p = __expf(s[km][rg] - mnew);
                s[km][rg] = p;
                tsum += p;
            }
        tsum += __shfl_xor(tsum, 16, 64);
        tsum += __shfl_xor(tsum, 32, 64);
        lrun = lrun * sc + tsum;
        mrun = mnew;
#pragma unroll
        for (int fm = 0; fm < 4; ++fm)
#pragma unroll
            for (int rg = 0; rg < 4; ++rg) o[fm][rg] *= sc;

        // P -> wave-private LDS rows (8B packed)
#pragma unroll
        for (int km = 0; km < 8; ++km) {
            uint2 pk;
            pk.x = (unsigned)f2b(s[km][0]) | ((unsigned)f2b(s[km][1]) << 16);
            pk.y = (unsigned)f2b(s[km][2]) | ((unsigned)f2b(s[km][3]) << 16);
            *(uint2*)(prow + km * 16 + q * 4) = pk;
        }
        asm volatile("s_waitcnt lgkmcnt(0)" ::: "memory");

        // PV: V fragments straight from global
        bf16x8 pf[4];
#pragma unroll
        for (int ks = 0; ks < 4; ++ks)
            pf[ks] = ld_frag(prow + ks * 32 + q * 8);
#pragma unroll
        for (int fm = 0; fm < 4; ++fm) {
            const u16* vp = vbase + (size_t)(fm * 16) * S_ + k0;
#pragma unroll
            for (int ks = 0; ks < 4; ++ks)
                o[fm] = __builtin_amdgcn_mfma_f32_16x16x32_bf16(
                    ld_frag(vp + ks * 32), pf[ks], o[fm], 0, 0, 0);
        }
    }

    float inv = 1.0f / lrun;
#pragma unroll
    for (int fm = 0; fm < 4; ++fm) {
        uint2 pk;
        pk.x = (unsigned)f2b(o[fm][0] * inv) | ((unsigned)f2b(o[fm][1] * inv) << 16);
        pk.y = (unsigned)f2b(o[fm][2] * inv) | ((unsigned)f2b(o[fm][3] * inv) << 16);
        *(uint2*)(Ob + ((size_t)(b * S_ + m0 + wave * 16 + r16)) * D_
                     + h * 64 + fm * 16 + q * 4) = pk;
    }
}

// ---------------------------------------------------------------------------
// LayerNorm: v = X1 + X2? + resid + cb?;  out = LN(v)*g + b. fp32 + bf16 out.
// Fuses split-K partial sum and the W2 column bias.
// ---------------------------------------------------------------------------
__global__ __launch_bounds__(256) void ln_k(const float* __restrict__ X1,
                                            const float* X2,
                                            const float* __restrict__ resid,
                                            const float* cb,
                                            const float* __restrict__ g,
                                            const float* __restrict__ be,
                                            float* out, u16* outb)
{
    const int wave = threadIdx.x >> 6, lane = threadIdx.x & 63;
    const int row = blockIdx.x * 4 + wave;
    const size_t ro = (size_t)row * D_;

    float v[8];
    float s = 0.0f;
#pragma unroll
    for (int i = 0; i < 8; ++i) {
        int c = i * 64 + lane;
        float x = X1[ro + c] + resid[ro + c];
        if (X2) x += X2[ro + c];
        if (cb) x += cb[c];
        v[i] = x;
        s += x;
    }
    s = wsum(s);
    float mean = s * (1.0f / D_);
    float s2 = 0.0f;
#pragma unroll
    for (int i = 0; i < 8; ++i) { float d = v[i] - mean; s2 += d * d; }
    s2 = wsum(s2);
    float inv = rsqrtf(s2 * (1.0f / D_) + 1e-6f);
#pragma unroll
    for (int i = 0; i < 8; ++i) {
        int c = i * 64 + lane;
        float y = (v[i] - mean) * inv * g[c] + be[c];
        out[ro + c]  = y;
        outb[ro + c] = f2b(y);
    }
}

// ---------------------------------------------------------------------------
// Host-side orchestration
// ---------------------------------------------------------------------------
extern "C" void kernel_launch(void* const* d_in, const int* in_sizes, int n_in,
                              void* d_out, int out_size, void* d_ws, size_t ws_size,
                              hipStream_t stream)
{
    (void)in_sizes; (void)n_in; (void)out_size; (void)ws_size;

    const int*   enc_in  = (const int*)d_in[0];
    const int*   dec_in  = (const int*)d_in[1];
    const float* emb_enc = (const float*)d_in[2];
    const float* emb_dec = (const float*)d_in[3];
    const float* proj_W  = (const float*)d_in[4];
    const float* Wt[2][12];
    for (int p = 0; p < 2; ++p)
        for (int j = 0; j < 12; ++j)
            Wt[p][j] = (const float*)d_in[5 + p * 12 + j];

    char* ws = (char*)d_ws;
    const size_t MB = 1024 * 1024;
    float* Xe   = (float*)(ws + 0 * MB);    // [2048,512] f32 (enc act / enc_out)
    float* Xd   = (float*)(ws + 4 * MB);    // [2048,512] f32 (dec act)
    float* Fo   = (float*)(ws + 8 * MB);    // pre-LN matmul out f32 (partial 0)
    u16*   HidB = (u16*)  (ws + 12 * MB);   // FFN hidden bf16 [2048,2048], 8 MB
    u16*   Qb   = (u16*)  (ws + 20 * MB);   // Q bf16 [2048,512]
    u16*   Kb   = (u16*)  (ws + 22 * MB);   // K bf16
    u16*   Vt   = (u16*)  (ws + 24 * MB);   // V transposed bf16 [32][64][512]
    u16*   AtnB = (u16*)  (ws + 26 * MB);   // attention out bf16 [2048,512]
    u16*   Xeb  = (u16*)  (ws + 28 * MB);   // enc act bf16 shadow
    u16*   Xdb  = (u16*)  (ws + 30 * MB);   // dec act bf16 shadow
    float* Fo2  = (float*)(ws + 32 * MB);   // split-K partial 1, f32

    // bf16 transposed weights: 76 MB ..
    u16* WTb = (u16*)(ws + 76 * MB);
    const size_t T66 = (size_t)6 * 512 * 512;
    u16* encAT  = WTb;                              // [4][6][512*512]
    u16* encW1T = encAT  + 4 * T66;                 // [6][2048*512]
    u16* encW2T = encW1T + 6 * (size_t)1048576;     // [6][512*2048]
    u16* decAT  = encW2T + 6 * (size_t)1048576;
    u16* decW1T = decAT  + 4 * T66;
    u16* decW2T = decW1T + 6 * (size_t)1048576;
    u16* projT  = decW2T + 6 * (size_t)1048576;     // [32000][512]

    const dim3 blk(256);

    // ---- weight pre-pass: fp32 [K,N] -> bf16 [N,K] ----
    for (int p = 0; p < 2; ++p) {
        u16* aT  = p ? decAT  : encAT;
        u16* w1T = p ? decW1T : encW1T;
        u16* w2T = p ? decW2T : encW2T;
        wt_k<<<dim3(8, 8, 24), blk, 0, stream>>>(Wt[p][0], Wt[p][1], Wt[p][2], Wt[p][3],
                                                 aT, 512, 512, 6);
        wt_k<<<dim3(32, 8, 6), blk, 0, stream>>>(Wt[p][6], 0, 0, 0, w1T, 512, 2048, 6);
        wt_k<<<dim3(8, 32, 6), blk, 0, stream>>>(Wt[p][8], 0, 0, 0, w2T, 2048, 512, 6);
    }
    wt_k<<<dim3(500, 8, 1), blk, 0, stream>>>(proj_W, 0, 0, 0, projT, 512, 32000, 1);

    const u16* Z = nullptr;
    // QKV: z=3, Ob=Q,K ; Tt=Vt
    auto qkv = [&](const u16* XqB, const u16* XkvB,
                   const u16* WqT, const u16* WkT, const u16* WvT) {
        dim3 g((2048 / 64) * (512 / 64), 1, 3);
        gemm64z_k<<<g, blk, 0, stream>>>(XqB, XkvB, XkvB, WqT, WkT, WvT,
                                         0, 0, 0, 0, 0, 0,
                                         Qb, Kb, 0, 0, 0, Vt,
                                         2048, 512, 512, 512, 512, 0);
    };
    // Wo: split-K=2, fp32 partials Fo/Fo2 (no bias)
    auto wo = [&](const u16* WoT) {
        dim3 g((2048 / 64) * (512 / 64), 1, 2);
        gemm64z_k<<<g, blk, 0, stream>>>(AtnB, AtnB + 256, Z, WoT, WoT + 256, Z,
                                         0, 0, 0, Fo, Fo2, 0,
                                         0, 0, 0, 0, 0, 0,
                                         2048, 512, 256, 512, 512, 0);
    };
    // W1: bf16 out + leaky + bias
    auto w1 = [&](const u16* XB, const u16* W1T, const float* c1) {
        dim3 g((2048 / 64) * (2048 / 64), 1, 1);
        gemm64z_k<<<g, blk, 0, stream>>>(XB, Z, Z, W1T, Z, Z,
                                         c1, 0, 0, 0, 0, 0,
                                         HidB, 0, 0, 0, 0, 0,
                                         2048, 2048, 512, 512, 512, 1);
    };
    // W2: split-K=2, fp32 partials (c2 bias folded into ln)
    auto w2 = [&](const u16* W2T) {
        dim3 g((2048 / 64) * (512 / 64), 1, 2);
        gemm64z_k<<<g, blk, 0, stream>>>(HidB, HidB + 1024, Z, W2T, W2T + 1024, Z,
                                         0, 0, 0, Fo, Fo2, 0,
                                         0, 0, 0, 0, 0, 0,
                                         2048, 512, 1024, 2048, 2048, 0);
    };
    auto attention = [&](const u16* XqB, const u16* XkvB, const int* mtok, int causal,
                         const u16* WqT, const u16* WkT, const u16* WvT) {
        qkv(XqB, XkvB, WqT, WkT, WvT);
        attn_k<<<dim3(8, 32), blk, 0, stream>>>(Qb, Kb, Vt, AtnB, mtok, causal);
    };

    // ---------------- encoder ----------------
    embed_k<<<B_ * S_, blk, 0, stream>>>(enc_in, emb_enc, Xe, Xeb);
    for (int l = 0; l < L_; ++l) {
        const u16* WqT = encAT + (size_t)(0 * 6 + l) * 262144;
        const u16* WkT = encAT + (size_t)(1 * 6 + l) * 262144;
        const u16* WvT = encAT + (size_t)(2 * 6 + l) * 262144;
        const u16* WoT = encAT + (size_t)(3 * 6 + l) * 262144;
        const u16* W1T = encW1T + (size_t)l * 1048576;
        const u16* W2T = encW2T + (size_t)l * 1048576;
        const float* g1 = Wt[0][4] + l * D_;
        const float* b1 = Wt[0][5] + l * D_;
        const float* c1 = Wt[0][7] + l * DFF_;
        const float* c2 = Wt[0][9] + l * D_;
        const float* g2 = Wt[0][10] + l * D_;
        const float* b2 = Wt[0][11] + l * D_;

        attention(Xeb, Xeb, enc_in, 0, WqT, WkT, WvT);
        wo(WoT);
        ln_k<<<dim3(512), blk, 0, stream>>>(Fo, Fo2, Xe, 0, g1, b1, Xe, Xeb);
        w1(Xeb, W1T, c1);
        w2(W2T);
        ln_k<<<dim3(512), blk, 0, stream>>>(Fo, Fo2, Xe, c2, g2, b2, Xe, Xeb);
    }

    // ---------------- decoder ----------------
    embed_k<<<B_ * S_, blk, 0, stream>>>(dec_in, emb_dec, Xd, Xdb);
    for (int l = 0; l < L_; ++l) {
        const u16* WqT = decAT + (size_t)(0 * 6 + l) * 262144;
        const u16* WkT = decAT + (size_t)(1 * 6 + l) * 262144;
        const u16* WvT = decAT + (size_t)(2 * 6 + l) * 262144;
        const u16* WoT = decAT + (size_t)(3 * 6 + l) * 262144;
        const u16* W1T = decW1T + (size_t)l * 1048576;
        const u16* W2T = decW2T + (size_t)l * 1048576;
        const float* g1 = Wt[1][4] + l * D_;
        const float* b1 = Wt[1][5] + l * D_;
        const float* c1 = Wt[1][7] + l * DFF_;
        const float* c2 = Wt[1][9] + l * D_;
        const float* g2 = Wt[1][10] + l * D_;
        const float* b2 = Wt[1][11] + l * D_;

        // self-attention (causal + dec pad)
        attention(Xdb, Xdb, dec_in, 1, WqT, WkT, WvT);
        wo(WoT);
        ln_k<<<dim3(512), blk, 0, stream>>>(Fo, Fo2, Xd, 0, g1, b1, Xd, Xdb);

        // cross-attention (same weights, K/V from enc_out, enc pad mask)
        attention(Xdb, Xeb, enc_in, 0, WqT, WkT, WvT);
        wo(WoT);
        ln_k<<<dim3(512), blk, 0, stream>>>(Fo, Fo2, Xd, 0, g1, b1, Xd, Xdb);

        // FFN
        w1(Xdb, W1T, c1);
        w2(W2T);
        ln_k<<<dim3(512), blk, 0, stream>>>(Fo, Fo2, Xd, c2, g2, b2, Xd, Xdb);
    }

    // final projection to vocab (fp32 out)
    {
        dim3 g((2048 / 128) * (VD_ / 128), 1, 1);
        gemm_k<<<g, blk, 0, stream>>>(Xdb, projT, (float*)d_out, 2048, VD_, 512);
    }
}